// Round 6
// baseline (482.305 us; speedup 1.0000x reference)
//
#include <hip/hip_runtime.h>

// LSTM discriminator: B=2048, T=1024, I=4, H=16, gates 4H=64.
// R6: 1 sequence per wave (2048 waves = 2 waves/SIMD for latency hiding).
// Lane l owns gate row l: rows 0-15=i, 16-31=f, 32-47=g, 48-63=o; j=l&15.
// Invariant: every lane holds h_{l&15} (h replicated in all 4 rows-of-16).
// h broadcast: rolling-XOR DPP within each row-of-16 (15 DPP), weights
// pre-permuted Wp[k]=W_hh[row][j^k] -> 16 FMA dot with static indexing.
// Gate gather (each lane needs i,f,g,o at its j): b16=ds_swizzle xor16,
// b32=v_permlane32_swap (VALU!), b48=swizzle(b32); 8 cndmask to map.
// R6 FIX: v_permlane32_swap_b32 swaps vdst.hi <-> vsrc.lo, so with both
// operands = v: pr[0]={v.lo,v.lo}, pr[1]={v.hi,v.hi}. Hi lanes take pr[0]
// (lo data), lo lanes take pr[1] (hi data). R4 had the select inverted ->
// xchg32 returned own value -> wrong gate routing (absmax 5.7e-2).
// Readout: p=h*Wd[j], DPP tree (xor1,xor2,ror4,ror8) -> all lanes hold dot.
// No LDS, no barriers, no delayed output.

#define T_DIM 1024
#define LOG2E 1.4426950408889634f

typedef __attribute__((ext_vector_type(2))) int i32x2;

__device__ __forceinline__ float fsig(float x) {
    float e = __builtin_amdgcn_exp2f(-x * LOG2E);
    return __builtin_amdgcn_rcpf(1.0f + e);
}

template<int CTRL>
__device__ __forceinline__ float dpp_f(float v) {
    int i = __float_as_int(v);
    return __int_as_float(__builtin_amdgcn_update_dpp(i, i, CTRL, 0xF, 0xF, false));
}
// DPP ctrl: quad_perm xor1=0xB1, xor2=0x4E, xor3=0x1B;
//           ROW_HALF_MIRROR=0x141 (j^7), ROW_MIRROR=0x140 (j^15);
//           ROW_ROR:4=0x124, ROW_ROR:8=0x128 (reduction rotations)

__device__ __forceinline__ float swz16(float v) {
    // ds_swizzle BitMode xor=16, and=0x1F: lane l <-> l^16 within each 32-group
    return __int_as_float(__builtin_amdgcn_ds_swizzle(__float_as_int(v), 0x401F));
}

__device__ __forceinline__ float xchg32(float v, bool hi32) {
    // value from lane l^32
#if __has_builtin(__builtin_amdgcn_permlane32_swap)
    i32x2 pr = __builtin_amdgcn_permlane32_swap(__float_as_int(v), __float_as_int(v), false, false);
    // swap is vdst.hi <-> vsrc.lo: pr[0]={v.lo,v.lo}, pr[1]={v.hi,v.hi}
    // hi lanes want lo data (pr[0]); lo lanes want hi data (pr[1])
    return __int_as_float(hi32 ? pr[0] : pr[1]);
#else
    int l = threadIdx.x & 63;
    return __int_as_float(__builtin_amdgcn_ds_bpermute(((l ^ 32) << 2), __float_as_int(v)));
#endif
}

__global__ __launch_bounds__(64) void lstm_disc_kernel(
    const float* __restrict__ x,      // [B, T, 4]
    const float* __restrict__ W_ih,   // [64, 4]
    const float* __restrict__ W_hh,   // [64, 16]
    const float* __restrict__ b_ih,   // [64]
    const float* __restrict__ b_hh,   // [64]
    const float* __restrict__ W_d,    // [1, 16]
    const float* __restrict__ b_d,    // [1]
    float* __restrict__ out)          // [B, T]
{
    const int l  = threadIdx.x;          // 0..63 = gate row
    const int j  = l & 15;               // hidden index
    const bool s1 = (l & 16) != 0;
    const bool s2 = (l & 32) != 0;
    const int batch = blockIdx.x;        // 1 sequence per wave

    // Pre-permuted row weights: Wp[k] pairs with broadcast value h_{j^k}
    float Wp[16];
#pragma unroll
    for (int k = 0; k < 16; ++k) Wp[k] = W_hh[l * 16 + (j ^ k)];
    const float4 Wx = *reinterpret_cast<const float4*>(W_ih + l * 4);
    const float bias = b_ih[l] + b_hh[l];
    const float wd = W_d[j];
    const float bd = b_d[0];
    const bool isg = s2 && !s1;                  // g-rows (32..47): tanh
    const float m2  = isg ? 2.0f : 1.0f;         // act = m*sig(m*x) - (m-1)
    const float m2n = isg ? -1.0f : 0.0f;

    const float4* xp = reinterpret_cast<const float4*>(x + (size_t)batch * (T_DIM * 4));
    float4 xv = xp[0];

    float h = 0.0f, c = 0.0f;
    float s0v = 0.f, s1v = 0.f, s2v = 0.f;

    for (int t4 = 0; t4 < T_DIM; t4 += 4) {
#pragma unroll
        for (int u = 0; u < 4; ++u) {
            const int t = t4 + u;
            const float4 xn = xp[(t + 1 < T_DIM) ? (t + 1) : (T_DIM - 1)];

            // x-projection + bias (independent of h -> schedules early)
            const float gx = fmaf(Wx.x, xv.x, fmaf(Wx.y, xv.y,
                               fmaf(Wx.z, xv.z, fmaf(Wx.w, xv.w, bias))));

            // ---- rolling-XOR broadcast of h + row dot (4 chains of 4) ----
            float a0 = fmaf(Wp[0], h, gx);
            const float v1 = dpp_f<0xB1>(h);      // j^1
            const float v2 = dpp_f<0x4E>(h);      // j^2
            const float v3 = dpp_f<0x1B>(h);      // j^3
            const float m7 = dpp_f<0x141>(h);     // j^7
            const float mF = dpp_f<0x140>(h);     // j^15
            float a1 = Wp[1] * v1;
            float a2 = Wp[2] * v2;
            float a3 = Wp[3] * v3;
            const float v6 = dpp_f<0xB1>(m7);     // j^6
            const float v5 = dpp_f<0x4E>(m7);     // j^5
            const float v4 = dpp_f<0x1B>(m7);     // j^4
            const float m8 = dpp_f<0x141>(mF);    // j^8
            a0 = fmaf(Wp[7], m7, a0);
            a1 = fmaf(Wp[6], v6, a1);
            a2 = fmaf(Wp[5], v5, a2);
            a3 = fmaf(Wp[4], v4, a3);
            const float vE = dpp_f<0xB1>(mF);     // j^14
            const float vD = dpp_f<0x4E>(mF);     // j^13
            const float vC = dpp_f<0x1B>(mF);     // j^12
            a0 = fmaf(Wp[15], mF, a0);
            a1 = fmaf(Wp[14], vE, a1);
            a2 = fmaf(Wp[13], vD, a2);
            a3 = fmaf(Wp[12], vC, a3);
            const float v9 = dpp_f<0xB1>(m8);     // j^9
            const float vA = dpp_f<0x4E>(m8);     // j^10
            const float vB = dpp_f<0x1B>(m8);     // j^11
            a0 = fmaf(Wp[8],  m8, a0);
            a1 = fmaf(Wp[9],  v9, a1);
            a2 = fmaf(Wp[10], vA, a2);
            a3 = fmaf(Wp[11], vB, a3);
            const float g = (a0 + a1) + (a2 + a3);

            // ---- own gate activation ----
            const float act = fmaf(m2, fsig(m2 * g), m2n);

            // ---- 4-way gather of (i,f,g,o) to every lane ----
            const float b16 = swz16(act);          // from l^16
            const float b32 = xchg32(act, s2);     // from l^32 (VALU permlane)
            const float b48 = swz16(b32);          // from l^48
            // ty0: own=i b16=f b32=g b48=o | ty1: own=f b16=i b32=o b48=g
            // ty2: own=g b16=o b32=i b48=f | ty3: own=o b16=g b32=f b48=i
            const float pa = s1 ? b16 : act;       // i (or g)
            const float pb = s1 ? b48 : b32;       // g (or i)
            const float ig = pa * pb;              // i*g
            const float f1 = s2 ? b48 : b16;
            const float f2 = s2 ? b32 : act;
            const float fg = s1 ? f2 : f1;         // f
            const float o1 = s2 ? b16 : b48;
            const float o2 = s2 ? act : b32;
            const float og = s1 ? o2 : o1;         // o

            // ---- cell update (every lane computes c_j, j=l&15) ----
            c = fmaf(fg, c, ig);
            const float tc = fmaf(2.0f, fsig(2.0f * c), -1.0f);   // tanh(c)
            h = og * tc;                                          // h_{l&15} everywhere

            // ---- readout: dot(h, W_d) via DPP reduction tree (off chain) ----
            float p = h * wd;
            p += dpp_f<0xB1>(p);                   // + j^1
            p += dpp_f<0x4E>(p);                   // + j^2  (quad sums)
            p += dpp_f<0x124>(p);                  // + ror4 (2 quads)
            p += dpp_f<0x128>(p);                  // + ror8 (all 4 -> full dot)
            const float oo = fsig(p + bd);

            if (u == 0) s0v = oo;
            else if (u == 1) s1v = oo;
            else if (u == 2) s2v = oo;
            else if (l == 0)
                *reinterpret_cast<float4*>(out + (size_t)batch * T_DIM + t4) =
                    make_float4(s0v, s1v, s2v, oo);

            xv = xn;
        }
    }
}

extern "C" void kernel_launch(void* const* d_in, const int* in_sizes, int n_in,
                              void* d_out, int out_size, void* d_ws, size_t ws_size,
                              hipStream_t stream) {
    const float* x    = (const float*)d_in[0];
    const float* W_ih = (const float*)d_in[1];
    const float* W_hh = (const float*)d_in[2];
    const float* b_ih = (const float*)d_in[3];
    const float* b_hh = (const float*)d_in[4];
    const float* W_d  = (const float*)d_in[5];
    const float* b_d  = (const float*)d_in[6];
    float* out = (float*)d_out;

    // 2048 blocks x 1 wave = 8 waves/CU = 2 waves/SIMD
    lstm_disc_kernel<<<2048, 64, 0, stream>>>(x, W_ih, W_hh, b_ih, b_hh, W_d, b_d, out);
}